// Round 9
// baseline (262.212 us; speedup 1.0000x reference)
//
#include <hip/hip_runtime.h>
#include <hip/hip_fp16.h>
#include <math.h>

#define HEADS 2
#define FDIM 128
#define INDIM 64
#define ODIM 32
#define NEG_SLOPE 0.2f
#define BSH 7                 // bucket = dst >> 7  (128 dsts/bucket)
#define BW  128
#define NBLK 128              // radix pass blocks

typedef _Float16 f16x8 __attribute__((ext_vector_type(8)));
typedef float f32x4 __attribute__((ext_vector_type(4)));
typedef float f32x2 __attribute__((ext_vector_type(2)));
union H8 { uint4 u; f16x8 v; __half2 h2[4]; };

__device__ __forceinline__ float elu1(float v) { return v > 0.f ? v : __expf(v) - 1.f; }

#define MFMA16(a, b, c) __builtin_amdgcn_mfma_f32_16x16x32_f16((a), (b), (c), 0, 0, 0)

// pack 4 fp32 -> 4 fp8 e4m3 bytes (gfx950 HW cvt)
__device__ __forceinline__ unsigned pack_fp8x4(float a, float b, float c, float d) {
    int p = __builtin_amdgcn_cvt_pk_fp8_f32(a, b, 0, false);
    p = __builtin_amdgcn_cvt_pk_fp8_f32(c, d, p, true);
    return (unsigned)p;
}

// ---------------- CSR build: two-pass radix by bucket, LDS-atomics only ----------------
__global__ __launch_bounds__(256) void k_hist2(const int* __restrict__ ei, int E_,
                                               int* __restrict__ cnt, int nb, int epb) {
    __shared__ int h[512];
    int t = threadIdx.x, blk = blockIdx.x;
    for (int i = t; i < nb; i += 256) h[i] = 0;
    __syncthreads();
    int e0 = blk * epb, e1 = min(E_, e0 + epb);
    for (int e = e0 + t; e < e1; e += 256)
        atomicAdd(&h[ei[E_ + e] >> BSH], 1);
    __syncthreads();
    for (int i = t; i < nb; i += 256) cnt[blk * nb + i] = h[i];
}

__global__ __launch_bounds__(512) void k_scanb(const int* __restrict__ cnt,
                                               int* __restrict__ bstart,
                                               int* __restrict__ base, int nb, int E_) {
    __shared__ int sc[512];
    int t = threadIdx.x;
    int tot = 0;
    if (t < nb)
        for (int k = 0; k < NBLK; ++k) tot += cnt[k * nb + t];
    sc[t] = tot;
    __syncthreads();
    for (int o = 1; o < 512; o <<= 1) {
        int add = (t >= o) ? sc[t - o] : 0;
        __syncthreads();
        sc[t] += add;
        __syncthreads();
    }
    int ex = sc[t] - tot;
    if (t < nb) {
        bstart[t] = ex;
        int run = ex;
        for (int k = 0; k < NBLK; ++k) {
            base[k * nb + t] = run;
            run += cnt[k * nb + t];
        }
    }
    if (t == 0) bstart[nb] = E_;
}

__global__ __launch_bounds__(256) void k_scatter2(const int* __restrict__ ei, int E_,
                                                  const int* __restrict__ base,
                                                  unsigned* __restrict__ ebuf,
                                                  int nb, int epb) {
    __shared__ int pcur[512];
    int t = threadIdx.x, blk = blockIdx.x;
    for (int i = t; i < nb; i += 256) pcur[i] = base[blk * nb + i];
    __syncthreads();
    int e0 = blk * epb, e1 = min(E_, e0 + epb);
    for (int e = e0 + t; e < e1; e += 256) {
        int s = ei[e], d = ei[E_ + e];
        int slot = atomicAdd(&pcur[d >> BSH], 1);
        ebuf[slot] = ((unsigned)(d & (BW - 1)) << 25) | (unsigned)s;
    }
}

__global__ __launch_bounds__(256) void k_bfill(const unsigned* __restrict__ ebuf,
                                               const int* __restrict__ bstart,
                                               int* __restrict__ offs,
                                               int* __restrict__ csr_src, int n, int E_) {
    __shared__ int hist[BW], sc[BW], pcur[BW];
    int b = blockIdx.x;
    int t = threadIdx.x;
    if (b == 0 && t == 0) offs[n] = E_;          // sentinel
    int base_ = bstart[b];
    int cnt = bstart[b + 1] - base_;
    int d0 = b << BSH;
    if (t < BW) hist[t] = 0;
    __syncthreads();
    for (int i = t; i < cnt; i += 256)
        atomicAdd(&hist[ebuf[base_ + i] >> 25], 1);
    __syncthreads();
    int v = (t < BW) ? hist[t] : 0;
    if (t < BW) sc[t] = v;
    __syncthreads();
    for (int o = 1; o < BW; o <<= 1) {
        int add = (t < BW && t >= o) ? sc[t - o] : 0;
        __syncthreads();
        if (t < BW) sc[t] += add;
        __syncthreads();
    }
    if (t < BW) {
        int abspos = base_ + sc[t] - v;
        pcur[t] = abspos;
        if (d0 + t < n) offs[d0 + t] = abspos;
    }
    __syncthreads();
    for (int i = t; i < cnt; i += 256) {
        unsigned u = ebuf[base_ + i];
        int slot = atomicAdd(&pcur[u >> 25], 1);
        csr_src[slot] = (int)(u & 0x1FFFFFFu);
    }
}

// ---------- weight precompute ----------
__global__ __launch_bounds__(128) void k_fuse_w(
    const float* __restrict__ W0,
    const float* __restrict__ fcw0, const float* __restrict__ fcb0, const float* __restrict__ W1,
    const float* __restrict__ fcw1, const float* __restrict__ fcb1,
    const float* __restrict__ out_w, const float* __restrict__ out_b,
    __half* __restrict__ W0T, __half* __restrict__ WfT, float* __restrict__ bf,
    __half* __restrict__ WfoT, float* __restrict__ bfo)
{
    int b = blockIdx.x, c = threadIdx.x;
    if (b < 128) {
        float acc = 0.f;
        for (int j = 0; j < 64; ++j) acc = fmaf(fcw0[b * 64 + j], W1[j * 128 + c], acc);
        WfT[c * 128 + b] = __float2half(acc);
    } else if (b == 128) {
        float acc = 0.f;
        for (int j = 0; j < 64; ++j) acc = fmaf(fcb0[j], W1[j * 128 + c], acc);
        bf[c] = acc;
    } else if (b < 257) {
        int k = b - 129;
        if (c < 32) {
            float acc = 0.f;
            for (int j = 0; j < 64; ++j) acc = fmaf(fcw1[k * 64 + j], out_w[j * 32 + c], acc);
            WfoT[c * 128 + k] = __float2half(acc);
        }
    } else if (b == 257) {
        if (c < 32) {
            float acc = 0.f;
            for (int j = 0; j < 64; ++j) acc = fmaf(fcb1[j], out_w[j * 32 + c], acc);
            bfo[c] = acc + out_b[c];
        }
    } else {
        int k = b - 258;
        W0T[c * 64 + k] = __float2half(W0[k * 128 + c]);
    }
}

// ---------- layer-1: xl(fp8) = x@W0 + a_src/a_dst, MFMA ----------
__global__ __launch_bounds__(256, 2) void k_mm_att1(
    const float* __restrict__ x, const __half* __restrict__ w0t,
    const float* __restrict__ att_src, const float* __restrict__ att_dst,
    unsigned char* __restrict__ xl, float* __restrict__ a_src, float* __restrict__ a_dst,
    int n, int ntiles, int nwaves)
{
    int lane = threadIdx.x & 63;
    int wid = blockIdx.x * 4 + (threadIdx.x >> 6);
    int m = lane & 15, q = lane >> 4;

    H8 A[8][2];
    #pragma unroll
    for (int nt = 0; nt < 8; ++nt)
        #pragma unroll
        for (int kt = 0; kt < 2; ++kt)
            A[nt][kt].u = *(const uint4*)(w0t + (size_t)(nt * 16 + m) * 64 + kt * 32 + q * 8);

    for (int t = wid; t < ntiles; t += nwaves) {
        int rb = t * 16;
        int row = rb + m; if (row >= n) row = n - 1;
        H8 B[2];
        #pragma unroll
        for (int kt = 0; kt < 2; ++kt) {
            const float4* p = (const float4*)(x + (size_t)row * 64 + kt * 32 + q * 8);
            float4 p0 = p[0], p1 = p[1];
            B[kt].h2[0] = __floats2half2_rn(p0.x, p0.y);
            B[kt].h2[1] = __floats2half2_rn(p0.z, p0.w);
            B[kt].h2[2] = __floats2half2_rn(p1.x, p1.y);
            B[kt].h2[3] = __floats2half2_rn(p1.z, p1.w);
        }
        f32x4 acc[8];
        #pragma unroll
        for (int nt = 0; nt < 8; ++nt) {
            acc[nt] = {0.f, 0.f, 0.f, 0.f};
            acc[nt] = MFMA16(A[nt][0].v, B[0].v, acc[nt]);
            acc[nt] = MFMA16(A[nt][1].v, B[1].v, acc[nt]);
        }
        float ps0 = 0.f, ps1 = 0.f, pd0 = 0.f, pd1 = 0.f;
        bool ok = (rb + m) < n;
        #pragma unroll
        for (int nt = 0; nt < 8; ++nt) {
            float4 asv = *(const float4*)(att_src + nt * 16 + q * 4);
            float4 adv = *(const float4*)(att_dst + nt * 16 + q * 4);
            f32x4 d = acc[nt];
            unsigned pk = pack_fp8x4(d[0], d[1], d[2], d[3]);
            if (ok) *(unsigned*)(xl + (size_t)(rb + m) * 128 + nt * 16 + q * 4) = pk;
            float cs = d[0] * asv.x + d[1] * asv.y + d[2] * asv.z + d[3] * asv.w;
            float cd = d[0] * adv.x + d[1] * adv.y + d[2] * adv.z + d[3] * adv.w;
            if (nt < 4) { ps0 += cs; pd0 += cd; } else { ps1 += cs; pd1 += cd; }
        }
        ps0 += __shfl_xor(ps0, 16, 64); ps0 += __shfl_xor(ps0, 32, 64);
        ps1 += __shfl_xor(ps1, 16, 64); ps1 += __shfl_xor(ps1, 32, 64);
        pd0 += __shfl_xor(pd0, 16, 64); pd0 += __shfl_xor(pd0, 32, 64);
        pd1 += __shfl_xor(pd1, 16, 64); pd1 += __shfl_xor(pd1, 32, 64);
        if (lane < 16 && ok) {
            *(float2*)(a_src + (size_t)(rb + m) * 2) = make_float2(ps0, ps1);
            *(float2*)(a_dst + (size_t)(rb + m) * 2) = make_float2(pd0, pd1);
        }
    }
}

// ---------- layer-2: xl(fp8) = elu(gat fp16)@Wf + bf + a_src/a_dst ----------
__global__ __launch_bounds__(256, 2) void k_mm_att2(
    const __half* __restrict__ g, const __half* __restrict__ wft, const float* __restrict__ bf,
    const float* __restrict__ att_src, const float* __restrict__ att_dst,
    unsigned char* __restrict__ xl, float* __restrict__ a_src, float* __restrict__ a_dst,
    int n, int ntiles, int nwaves)
{
    int lane = threadIdx.x & 63;
    int wid = blockIdx.x * 4 + (threadIdx.x >> 6);
    int m = lane & 15, q = lane >> 4;

    H8 A[8][4];
    #pragma unroll
    for (int nt = 0; nt < 8; ++nt)
        #pragma unroll
        for (int kt = 0; kt < 4; ++kt)
            A[nt][kt].u = *(const uint4*)(wft + (size_t)(nt * 16 + m) * 128 + kt * 32 + q * 8);

    for (int t = wid; t < ntiles; t += nwaves) {
        int rb = t * 16;
        int row = rb + m; if (row >= n) row = n - 1;
        H8 B[4];
        #pragma unroll
        for (int kt = 0; kt < 4; ++kt) {
            H8 raw;
            raw.u = *(const uint4*)(g + (size_t)row * 128 + kt * 32 + q * 8);
            #pragma unroll
            for (int r = 0; r < 4; ++r) {
                float2 f = __half22float2(raw.h2[r]);
                B[kt].h2[r] = __floats2half2_rn(elu1(f.x), elu1(f.y));
            }
        }
        f32x4 acc[8];
        #pragma unroll
        for (int nt = 0; nt < 8; ++nt) {
            acc[nt] = {0.f, 0.f, 0.f, 0.f};
            #pragma unroll
            for (int kt = 0; kt < 4; ++kt)
                acc[nt] = MFMA16(A[nt][kt].v, B[kt].v, acc[nt]);
        }
        float ps0 = 0.f, ps1 = 0.f, pd0 = 0.f, pd1 = 0.f;
        bool ok = (rb + m) < n;
        #pragma unroll
        for (int nt = 0; nt < 8; ++nt) {
            float4 bfv = *(const float4*)(bf + nt * 16 + q * 4);
            float4 asv = *(const float4*)(att_src + nt * 16 + q * 4);
            float4 adv = *(const float4*)(att_dst + nt * 16 + q * 4);
            f32x4 d = acc[nt];
            d[0] += bfv.x; d[1] += bfv.y; d[2] += bfv.z; d[3] += bfv.w;
            unsigned pk = pack_fp8x4(d[0], d[1], d[2], d[3]);
            if (ok) *(unsigned*)(xl + (size_t)(rb + m) * 128 + nt * 16 + q * 4) = pk;
            float cs = d[0] * asv.x + d[1] * asv.y + d[2] * asv.z + d[3] * asv.w;
            float cd = d[0] * adv.x + d[1] * adv.y + d[2] * adv.z + d[3] * adv.w;
            if (nt < 4) { ps0 += cs; pd0 += cd; } else { ps1 += cs; pd1 += cd; }
        }
        ps0 += __shfl_xor(ps0, 16, 64); ps0 += __shfl_xor(ps0, 32, 64);
        ps1 += __shfl_xor(ps1, 16, 64); ps1 += __shfl_xor(ps1, 32, 64);
        pd0 += __shfl_xor(pd0, 16, 64); pd0 += __shfl_xor(pd0, 32, 64);
        pd1 += __shfl_xor(pd1, 16, 64); pd1 += __shfl_xor(pd1, 32, 64);
        if (lane < 16 && ok) {
            *(float2*)(a_src + (size_t)(rb + m) * 2) = make_float2(ps0, ps1);
            *(float2*)(a_dst + (size_t)(rb + m) * 2) = make_float2(pd0, pd1);
        }
    }
}

// ---------- gather v5: grid-stride, fp8 xl, 16 edges in flight, fp32 acc ----------
__global__ __launch_bounds__(256, 4) void k_gather(
    const int* __restrict__ offs, const int* __restrict__ csr_src, int E_,
    const unsigned char* __restrict__ xl, const float* __restrict__ a_src,
    const float* __restrict__ a_dst, const float* __restrict__ bias,
    __half* __restrict__ out, int n, int ngrp)
{
    int t = threadIdx.x;
    int lane = t & 63;
    int eh = lane >> 4;          // edge slot 0..3
    int cq = lane & 15;          // channels cq*8 .. cq*8+7
    int h = cq >> 3;
    const float4* bp = (const float4*)(bias + cq * 8);
    float4 b0 = bp[0], b1 = bp[1];

    for (int grp = blockIdx.x; grp < ngrp; grp += gridDim.x) {
        int d = grp * 4 + (t >> 6);
        if (d >= n) continue;
        float ad = a_dst[d * 2 + h];
        int start = offs[d];
        int end = offs[d + 1];          // sentinel at offs[n]
        float acc[8] = {0.f, 0.f, 0.f, 0.f, 0.f, 0.f, 0.f, 0.f};
        float den = 0.f;
        for (int j0 = start; j0 < end; j0 += 16) {
            int s0_, s1_, s2_, s3_;
            int ja = j0 + eh, jb = j0 + 4 + eh, jc = j0 + 8 + eh, jd = j0 + 12 + eh;
            bool va = ja < end, vb = jb < end, vc = jc < end, vd = jd < end;
            s0_ = va ? csr_src[ja] : d;
            s1_ = vb ? csr_src[jb] : d;
            s2_ = vc ? csr_src[jc] : d;
            s3_ = vd ? csr_src[jd] : d;
            uint2 u0 = *(const uint2*)(xl + (size_t)s0_ * 128 + cq * 8);
            uint2 u1 = *(const uint2*)(xl + (size_t)s1_ * 128 + cq * 8);
            uint2 u2 = *(const uint2*)(xl + (size_t)s2_ * 128 + cq * 8);
            uint2 u3 = *(const uint2*)(xl + (size_t)s3_ * 128 + cq * 8);
            float w0 = a_src[s0_ * 2 + h] + ad;
            float w1 = a_src[s1_ * 2 + h] + ad;
            float w2 = a_src[s2_ * 2 + h] + ad;
            float w3 = a_src[s3_ * 2 + h] + ad;
            w0 = (w0 >= 0.f) ? w0 : NEG_SLOPE * w0;
            w1 = (w1 >= 0.f) ? w1 : NEG_SLOPE * w1;
            w2 = (w2 >= 0.f) ? w2 : NEG_SLOPE * w2;
            w3 = (w3 >= 0.f) ? w3 : NEG_SLOPE * w3;
            w0 = va ? __expf(w0) : 0.f;
            w1 = vb ? __expf(w1) : 0.f;
            w2 = vc ? __expf(w2) : 0.f;
            w3 = vd ? __expf(w3) : 0.f;
            #define ACC8(u, w) { \
                f32x2 c0 = __builtin_amdgcn_cvt_pk_f32_fp8((u).x, 0); \
                f32x2 c1 = __builtin_amdgcn_cvt_pk_f32_fp8((u).x, 1); \
                f32x2 c2 = __builtin_amdgcn_cvt_pk_f32_fp8((u).y, 0); \
                f32x2 c3 = __builtin_amdgcn_cvt_pk_f32_fp8((u).y, 1); \
                acc[0] = fmaf((w), c0.x, acc[0]); acc[1] = fmaf((w), c0.y, acc[1]); \
                acc[2] = fmaf((w), c1.x, acc[2]); acc[3] = fmaf((w), c1.y, acc[3]); \
                acc[4] = fmaf((w), c2.x, acc[4]); acc[5] = fmaf((w), c2.y, acc[5]); \
                acc[6] = fmaf((w), c3.x, acc[6]); acc[7] = fmaf((w), c3.y, acc[7]); }
            ACC8(u0, w0); ACC8(u1, w1); ACC8(u2, w2); ACC8(u3, w3);
            den += (w0 + w1) + (w2 + w3);
        }
        if (eh == 0) {   // self-loop, counted once
            float a = a_src[d * 2 + h] + ad;
            a = (a >= 0.f) ? a : NEG_SLOPE * a;
            float w = __expf(a);
            uint2 u = *(const uint2*)(xl + (size_t)d * 128 + cq * 8);
            ACC8(u, w);
            den += w;
        }
        #undef ACC8
        #pragma unroll
        for (int i = 0; i < 8; ++i) {
            acc[i] += __shfl_xor(acc[i], 16, 64);
            acc[i] += __shfl_xor(acc[i], 32, 64);
        }
        den += __shfl_xor(den, 16, 64);
        den += __shfl_xor(den, 32, 64);
        if (eh == 0) {
            float inv = 1.f / (den + 1e-16f);
            H8 pk;
            pk.h2[0] = __floats2half2_rn(fmaf(acc[0], inv, b0.x), fmaf(acc[1], inv, b0.y));
            pk.h2[1] = __floats2half2_rn(fmaf(acc[2], inv, b0.z), fmaf(acc[3], inv, b0.w));
            pk.h2[2] = __floats2half2_rn(fmaf(acc[4], inv, b1.x), fmaf(acc[5], inv, b1.y));
            pk.h2[3] = __floats2half2_rn(fmaf(acc[6], inv, b1.z), fmaf(acc[7], inv, b1.w));
            *(uint4*)(out + (size_t)d * 128 + cq * 8) = pk.u;
        }
    }
}

// ---------- head: softmax(elu(gat2 fp16)@Wfo + bfo + gumbel), MFMA ----------
__global__ __launch_bounds__(256, 2) void k_mm_final(
    const __half* __restrict__ g, const __half* __restrict__ wfot, const float* __restrict__ bfo,
    const float* __restrict__ gu, float* __restrict__ out, int n, int ntiles, int nwaves)
{
    int lane = threadIdx.x & 63;
    int wid = blockIdx.x * 4 + (threadIdx.x >> 6);
    int m = lane & 15, q = lane >> 4;

    H8 A[2][4];
    #pragma unroll
    for (int nt = 0; nt < 2; ++nt)
        #pragma unroll
        for (int kt = 0; kt < 4; ++kt)
            A[nt][kt].u = *(const uint4*)(wfot + (size_t)(nt * 16 + m) * 128 + kt * 32 + q * 8);

    for (int t = wid; t < ntiles; t += nwaves) {
        int rb = t * 16;
        int row = rb + m; if (row >= n) row = n - 1;
        H8 B[4];
        #pragma unroll
        for (int kt = 0; kt < 4; ++kt) {
            H8 raw;
            raw.u = *(const uint4*)(g + (size_t)row * 128 + kt * 32 + q * 8);
            #pragma unroll
            for (int r = 0; r < 4; ++r) {
                float2 f = __half22float2(raw.h2[r]);
                B[kt].h2[r] = __floats2half2_rn(elu1(f.x), elu1(f.y));
            }
        }
        f32x4 acc[2];
        #pragma unroll
        for (int nt = 0; nt < 2; ++nt) {
            acc[nt] = {0.f, 0.f, 0.f, 0.f};
            #pragma unroll
            for (int kt = 0; kt < 4; ++kt)
                acc[nt] = MFMA16(A[nt][kt].v, B[kt].v, acc[nt]);
        }
        float z[8];
        #pragma unroll
        for (int nt = 0; nt < 2; ++nt) {
            float4 bv = *(const float4*)(bfo + nt * 16 + q * 4);
            float4 uv = *(const float4*)(gu + (size_t)row * 32 + nt * 16 + q * 4);
            z[nt * 4 + 0] = acc[nt][0] + bv.x - __logf(-__logf(uv.x + 1e-20f) + 1e-20f);
            z[nt * 4 + 1] = acc[nt][1] + bv.y - __logf(-__logf(uv.y + 1e-20f) + 1e-20f);
            z[nt * 4 + 2] = acc[nt][2] + bv.z - __logf(-__logf(uv.z + 1e-20f) + 1e-20f);
            z[nt * 4 + 3] = acc[nt][3] + bv.w - __logf(-__logf(uv.w + 1e-20f) + 1e-20f);
        }
        float mx = z[0];
        #pragma unroll
        for (int i = 1; i < 8; ++i) mx = fmaxf(mx, z[i]);
        mx = fmaxf(mx, __shfl_xor(mx, 16, 64));
        mx = fmaxf(mx, __shfl_xor(mx, 32, 64));
        float sum = 0.f;
        #pragma unroll
        for (int i = 0; i < 8; ++i) { z[i] = __expf(z[i] - mx); sum += z[i]; }
        sum += __shfl_xor(sum, 16, 64);
        sum += __shfl_xor(sum, 32, 64);
        float inv = 1.f / sum;
        if (rb + m < n) {
            #pragma unroll
            for (int nt = 0; nt < 2; ++nt) {
                float4 o = make_float4(z[nt * 4 + 0] * inv, z[nt * 4 + 1] * inv,
                                       z[nt * 4 + 2] * inv, z[nt * 4 + 3] * inv);
                *(float4*)(out + (size_t)(rb + m) * 32 + nt * 16 + q * 4) = o;
            }
        }
    }
}

extern "C" void kernel_launch(void* const* d_in, const int* in_sizes, int n_in,
                              void* d_out, int out_size, void* d_ws, size_t ws_size,
                              hipStream_t stream) {
    const float* x        = (const float*)d_in[0];
    const int*   ei       = (const int*)  d_in[1];
    const float* W0       = (const float*)d_in[2];
    const float* att_src0 = (const float*)d_in[3];
    const float* att_dst0 = (const float*)d_in[4];
    const float* bias0    = (const float*)d_in[5];
    const float* fcw0     = (const float*)d_in[6];
    const float* fcb0     = (const float*)d_in[7];
    const float* W1       = (const float*)d_in[8];
    const float* att_src1 = (const float*)d_in[9];
    const float* att_dst1 = (const float*)d_in[10];
    const float* bias1    = (const float*)d_in[11];
    const float* fcw1     = (const float*)d_in[12];
    const float* fcb1     = (const float*)d_in[13];
    const float* out_w    = (const float*)d_in[14];
    const float* out_b    = (const float*)d_in[15];
    const float* gu       = (const float*)d_in[16];

    const int N_ = in_sizes[0] / INDIM;
    const int E_ = in_sizes[1] / 2;
    const int NB = (N_ + BW - 1) / BW;            // buckets (<= 512)

    float* ws = (float*)d_ws;
    size_t off = 0;
    unsigned char* xl = (unsigned char*)(ws + off); off += (size_t)N_ * 32;  // fp8, 128 B/row
    __half* gat = (__half*)(ws + off); off += (size_t)N_ * 64;
    float* a_src = ws + off; off += (size_t)N_ * HEADS;
    float* a_dst = ws + off; off += (size_t)N_ * HEADS;
    __half* W0T  = (__half*)(ws + off); off += 128 * 64 / 2;
    __half* WfT  = (__half*)(ws + off); off += 128 * 128 / 2;
    __half* WfoT = (__half*)(ws + off); off += 32 * 128 / 2;
    float* bf    = ws + off; off += 128;
    float* bfo   = ws + off; off += 32;
    int* cnt     = (int*)(ws + off); off += (size_t)NB * NBLK;
    int* base    = (int*)(ws + off); off += (size_t)NB * NBLK;
    int* bstart  = (int*)(ws + off); off += NB + 1;
    int* offs    = (int*)(ws + off); off += N_ + 1;
    int* csr_src = (int*)(ws + off); off += E_;
    unsigned* ebuf = (unsigned*)(ws + off); off += E_;

    const int B = 256;
    dim3 blk(B);
    int ngrp   = (N_ + 3) / 4;
    int g_gath = 2048;
    int ntiles = (N_ + 15) / 16;
    int GMM    = 384;
    int nwaves = GMM * 4;
    int epb    = (E_ + NBLK - 1) / NBLK;

    // ---- CSR build: two-pass radix (LDS atomics only) ----
    k_hist2    <<<NBLK, blk, 0, stream>>>(ei, E_, cnt, NB, epb);
    k_scanb    <<<1, dim3(512), 0, stream>>>(cnt, bstart, base, NB, E_);
    k_scatter2 <<<NBLK, blk, 0, stream>>>(ei, E_, base, ebuf, NB, epb);
    k_bfill    <<<NB, blk, 0, stream>>>(ebuf, bstart, offs, csr_src, N_, E_);
    k_fuse_w   <<<322, dim3(128), 0, stream>>>(W0, fcw0, fcb0, W1, fcw1, fcb1, out_w, out_b,
                                               W0T, WfT, bf, WfoT, bfo);

    // ---- layer 1 ----
    k_mm_att1 <<<GMM,    blk, 0, stream>>>(x, W0T, att_src0, att_dst0, xl, a_src, a_dst,
                                           N_, ntiles, nwaves);
    k_gather  <<<g_gath, blk, 0, stream>>>(offs, csr_src, E_, xl, a_src, a_dst, bias0, gat, N_, ngrp);

    // ---- layer 2 (fc0 fused via WfT) ----
    k_mm_att2 <<<GMM,    blk, 0, stream>>>(gat, WfT, bf, att_src1, att_dst1, xl, a_src, a_dst,
                                           N_, ntiles, nwaves);
    k_gather  <<<g_gath, blk, 0, stream>>>(offs, csr_src, E_, xl, a_src, a_dst, bias1, gat, N_, ngrp);

    // ---- head (fc1 + out fused via WfoT) ----
    k_mm_final <<<GMM,   blk, 0, stream>>>(gat, WfoT, bfo, gu, (float*)d_out, N_, ntiles, nwaves);
}